// Round 7
// baseline (278.828 us; speedup 1.0000x reference)
//
#include <hip/hip_runtime.h>
#include <hip/hip_cooperative_groups.h>

namespace cg = cooperative_groups;

#define B   2
#define C   256
#define CM  64     // compressed channels
#define CE  100    // encoder out channels
#define H   40
#define W   40
#define HW  1600
#define KK  25     // K*K

// ===========================================================================
// Stage bodies (shared by the fused cooperative kernel and the 3-kernel
// fallback). Verbatim logic from the round-5 verified kernels.
// ===========================================================================

__device__ __forceinline__ void stageA_body(
    int u, int tid, float* smem,
    const float* __restrict__ x, const float* __restrict__ wc,
    float* __restrict__ pc) {
  const int t = u % 25, ich = (u / 25) % 4, b = u / 100;
  float* xs  = smem;          // [64 icl][64 px]
  float* wsA = smem + 4096;   // [64 icl][64 oc]

  const float4* x4 = (const float4*)(x + ((size_t)b * C + ich * 64) * HW + t * 64);
#pragma unroll
  for (int i = 0; i < 4; i++) {
    int idx = tid + i * 256;
    ((float4*)xs)[idx] = x4[(idx >> 4) * 400 + (idx & 15)];
  }
  const float4* w4 = (const float4*)wc;
#pragma unroll
  for (int i = 0; i < 4; i++) {
    int idx = tid + i * 256;
    int icq = idx >> 6, oc = idx & 63;
    float4 f = w4[oc * 64 + ich * 16 + icq];
    wsA[(icq * 4 + 0) * 64 + oc] = f.x;
    wsA[(icq * 4 + 1) * 64 + oc] = f.y;
    wsA[(icq * 4 + 2) * 64 + oc] = f.z;
    wsA[(icq * 4 + 3) * 64 + oc] = f.w;
  }
  __syncthreads();

  const int ty = tid >> 4, tx = tid & 15;
  float acc[4][4];
#pragma unroll
  for (int i = 0; i < 4; i++)
#pragma unroll
    for (int j = 0; j < 4; j++) acc[i][j] = 0.f;

#pragma unroll 4
  for (int icl = 0; icl < 64; icl++) {
    float4 a = *(const float4*)&wsA[icl * 64 + ty * 4];
    float4 bb = *(const float4*)&xs[icl * 64 + tx * 4];
    float av[4] = {a.x, a.y, a.z, a.w};
    float bv[4] = {bb.x, bb.y, bb.z, bb.w};
#pragma unroll
    for (int i = 0; i < 4; i++)
#pragma unroll
      for (int j = 0; j < 4; j++) acc[i][j] += av[i] * bv[j];
  }

  float* o = pc + ((size_t)ich * B + b) * CM * HW + t * 64 + tx * 4;
#pragma unroll
  for (int j = 0; j < 4; j++)
    *(float4*)&o[(size_t)(ty * 4 + j) * HW] =
        make_float4(acc[j][0], acc[j][1], acc[j][2], acc[j][3]);
}

__device__ __forceinline__ void stageB_body(
    int u, int tid, float* smem,
    const float* __restrict__ pc, const float* __restrict__ we,
    float* __restrict__ encP) {
  const int tile = u % 25, ocq = (u / 25) % 4, icq = u / 100;
  const int ty5 = tile / 5, tx5 = tile % 5;
  float* cs   = smem;          // [2 b][16 icl][10x10]
  float* wsb  = smem + 3200;   // [16 icl][9 tap][28 oc]
  float* pacc = smem;          // alias for reduction

  for (int i = tid; i < 3200; i += 256) {
    int bb = i / 1600, r = i - bb * 1600;
    int icl = r / 100, rr = r - icl * 100;
    int yy = rr / 10, xx = rr - yy * 10;
    int gy = ty5 * 8 + yy - 1, gx = tx5 * 8 + xx - 1;
    float v = 0.f;
    if (gy >= 0 && gy < H && gx >= 0 && gx < W) {
      int o = bb * 102400 + (icq * 16 + icl) * HW + gy * W + gx;
      v = pc[o] + pc[204800 + o] + pc[409600 + o] + pc[614400 + o];
    }
    cs[i] = v;
  }
  const float* wb = we + (size_t)(ocq * 25) * 576 + (size_t)(icq * 16) * 9;
  for (int i = tid; i < 3600; i += 256) {
    int ol = i / 144, r = i - ol * 144;
    wsb[r * 28 + ol] = wb[ol * 576 + r];
  }
  __syncthreads();

  const int wv = tid >> 6, lane = tid & 63, py = lane >> 3, px = lane & 7;
  float acc[50];
#pragma unroll
  for (int j = 0; j < 50; j++) acc[j] = 0.f;

#pragma unroll 1
  for (int t = 0; t < 4; t++) {
    const int icl = wv * 4 + t;
    const float* c0 = &cs[icl * 100 + py * 10 + px];
    const float* c1 = c0 + 1600;
    const float* wrow = &wsb[icl * 9 * 28];
#pragma unroll
    for (int dy = 0; dy < 3; dy++) {
#pragma unroll
      for (int dx = 0; dx < 3; dx++) {
        float x0 = c0[dy * 10 + dx];
        float x1 = c1[dy * 10 + dx];
        const float* wp = &wrow[(dy * 3 + dx) * 28];
        float4 w0 = *(const float4*)&wp[0],  w1 = *(const float4*)&wp[4];
        float4 w2 = *(const float4*)&wp[8],  w3 = *(const float4*)&wp[12];
        float4 w4v = *(const float4*)&wp[16], w5 = *(const float4*)&wp[20];
        float w6 = wp[24];
        acc[0]  += x0 * w0.x;  acc[1]  += x0 * w0.y;  acc[2]  += x0 * w0.z;  acc[3]  += x0 * w0.w;
        acc[4]  += x0 * w1.x;  acc[5]  += x0 * w1.y;  acc[6]  += x0 * w1.z;  acc[7]  += x0 * w1.w;
        acc[8]  += x0 * w2.x;  acc[9]  += x0 * w2.y;  acc[10] += x0 * w2.z;  acc[11] += x0 * w2.w;
        acc[12] += x0 * w3.x;  acc[13] += x0 * w3.y;  acc[14] += x0 * w3.z;  acc[15] += x0 * w3.w;
        acc[16] += x0 * w4v.x; acc[17] += x0 * w4v.y; acc[18] += x0 * w4v.z; acc[19] += x0 * w4v.w;
        acc[20] += x0 * w5.x;  acc[21] += x0 * w5.y;  acc[22] += x0 * w5.z;  acc[23] += x0 * w5.w;
        acc[24] += x0 * w6;
        acc[25] += x1 * w0.x;  acc[26] += x1 * w0.y;  acc[27] += x1 * w0.z;  acc[28] += x1 * w0.w;
        acc[29] += x1 * w1.x;  acc[30] += x1 * w1.y;  acc[31] += x1 * w1.z;  acc[32] += x1 * w1.w;
        acc[33] += x1 * w2.x;  acc[34] += x1 * w2.y;  acc[35] += x1 * w2.z;  acc[36] += x1 * w2.w;
        acc[37] += x1 * w3.x;  acc[38] += x1 * w3.y;  acc[39] += x1 * w3.z;  acc[40] += x1 * w3.w;
        acc[41] += x1 * w4v.x; acc[42] += x1 * w4v.y; acc[43] += x1 * w4v.z; acc[44] += x1 * w4v.w;
        acc[45] += x1 * w5.x;  acc[46] += x1 * w5.y;  acc[47] += x1 * w5.z;  acc[48] += x1 * w5.w;
        acc[49] += x1 * w6;
      }
    }
  }

  __syncthreads();
  if (wv == 1 || wv == 3) {
    const int slot = wv >> 1;
#pragma unroll
    for (int j = 0; j < 50; j++) pacc[slot * 3200 + j * 64 + lane] = acc[j];
  }
  __syncthreads();
  if (wv == 0 || wv == 2) {
    const int slot = wv >> 1;
#pragma unroll
    for (int j = 0; j < 50; j++) acc[j] += pacc[slot * 3200 + j * 64 + lane];
  }
  __syncthreads();
  if (wv == 2) {
#pragma unroll
    for (int j = 0; j < 50; j++) pacc[j * 64 + lane] = acc[j];
  }
  __syncthreads();
  if (wv == 0) {
    const int base_px = (ty5 * 8 + py) * W + tx5 * 8 + px;
#pragma unroll
    for (int bb = 0; bb < 2; bb++)
#pragma unroll
      for (int ol = 0; ol < 25; ol++)
        encP[(((size_t)icq * 2 + bb) * CE + ocq * 25 + ol) * HW + base_px] =
            acc[bb * 25 + ol] + pacc[(bb * 25 + ol) * 64 + lane];
  }
}

__device__ __forceinline__ void stageC_body(
    int u, int tid, float* smem,
    const float* __restrict__ x, const float* __restrict__ encP,
    float* __restrict__ out) {
  const int bx = u % 80;
  const int i0 = bx >> 1;
  const int jh = bx & 1;
  const int cq = (u / 80) % 4;
  const int b = u / 320;
  float* wlds = smem;          // [20 j0l][25 k][4 d]
  float* xsm  = smem + 2000;   // [64 c][121]

  if (tid < 80) {
    const int e = jh * 80 + tid;
    const int j0 = e >> 2, d = e & 3;
    const int off = ((e >= 80) ? 2 : 0) + (e & 1);
    const int col = ((e >= 80) ? (j0 - 20) : j0) * 2 + (d >> 1);
    const float* ep = encP + (size_t)b * CE * HW + i0 * W + col;
    float v[KK];
    float m = -1e30f;
#pragma unroll
    for (int k = 0; k < KK; k++) {
      int o = (k * 4 + off) * HW;
      v[k] = ep[o] + ep[320000 + o] + ep[640000 + o] + ep[960000 + o];
      m = fmaxf(m, v[k]);
    }
    float s = 0.f;
#pragma unroll
    for (int k = 0; k < KK; k++) {
      v[k] = expf(v[k] - m);
      s += v[k];
    }
    const float inv = 1.f / s;
    const int j0l = j0 - jh * 20;
#pragma unroll
    for (int k = 0; k < KK; k++) wlds[(j0l * KK + k) * 4 + d] = v[k] * inv;
  }

  const float* xb = x + ((size_t)b * C + cq * 64) * HW;
  for (int i = tid; i < 64 * 120; i += 256) {
    int c = i / 120;
    int rr = i % 120;
    int r = rr / 24, t = rr % 24;
    int gy = i0 - 2 + r;
    int gx = jh * 20 + t - 2;
    float v = 0.f;
    if (gy >= 0 && gy < H && gx >= 0 && gx < W) v = xb[c * HW + gy * W + gx];
    xsm[c * 121 + r * 24 + t] = v;
  }
  __syncthreads();

  const int wv = tid >> 6;
  const int lane = tid & 63;
  const int j0b = wv * 5;
  const float* xrow = &xsm[lane * 121];
  float* ob = out + (((size_t)b * C + cq * 64 + lane) * 6400) + i0 * 160;

  float a[5][4];
#pragma unroll
  for (int jj = 0; jj < 5; jj++)
#pragma unroll
    for (int d = 0; d < 4; d++) a[jj][d] = 0.f;

#pragma unroll
  for (int ki = 0; ki < 5; ki++) {
    float xv[9];
    const float* xr = &xrow[ki * 24 + j0b];
#pragma unroll
    for (int q = 0; q < 9; q++) xv[q] = xr[q];
    const float* wrow = &wlds[(j0b * KK + ki * 5) * 4];
#pragma unroll
    for (int jj = 0; jj < 5; jj++) {
#pragma unroll
      for (int kj = 0; kj < 5; kj++) {
        float4 w4 = *(const float4*)&wrow[(jj * KK + kj) * 4];
        float xvv = xv[jj + kj];
        a[jj][0] += xvv * w4.x;
        a[jj][1] += xvv * w4.y;
        a[jj][2] += xvv * w4.z;
        a[jj][3] += xvv * w4.w;
      }
    }
  }
#pragma unroll
  for (int jj = 0; jj < 5; jj++)
    *(float4*)&ob[(jh * 20 + j0b + jj) * 4] =
        make_float4(a[jj][0], a[jj][1], a[jj][2], a[jj][3]);
}

// ===========================================================================
// Fused cooperative kernel: 256 persistent blocks (fits even a 1-block/CU
// occupancy model), each serially processing its stage units; grid syncs
// between stages.
// ===========================================================================
__global__ __launch_bounds__(256) void k_fused(
    const float* __restrict__ x, const float* __restrict__ wc,
    const float* __restrict__ we, float* __restrict__ pc,
    float* __restrict__ encP, float* __restrict__ out) {
  __shared__ __align__(16) float smem[9744];   // 38.98 KB arena (max of stages)
  const int tid = threadIdx.x;
  const int bid = blockIdx.x;                  // [0,256)
  cg::grid_group grid = cg::this_grid();

  if (bid < 200) stageA_body(bid, tid, smem, x, wc, pc);
  __syncthreads();
  __threadfence();
  grid.sync();

  for (int u = bid; u < 400; u += 256) {
    stageB_body(u, tid, smem, pc, we, encP);
    __syncthreads();                           // smem reuse across iterations
  }
  __threadfence();
  grid.sync();

  for (int u = bid; u < 640; u += 256) {
    stageC_body(u, tid, smem, x, encP, out);
    __syncthreads();                           // smem reuse across iterations
  }
}

// ===========================================================================
// Fallback standalone kernels (round-5 verified structure).
// ===========================================================================
__global__ __launch_bounds__(256) void k1_conv1x1(
    const float* __restrict__ x, const float* __restrict__ w,
    float* __restrict__ pc) {
  __shared__ __align__(16) float smem[8192];
  stageA_body(blockIdx.x, threadIdx.x, smem, x, w, pc);
}

__global__ __launch_bounds__(256) void k2_conv3x3(
    const float* __restrict__ pc, const float* __restrict__ w,
    float* __restrict__ encP) {
  __shared__ __align__(16) float smem[7232];
  stageB_body(blockIdx.x, threadIdx.x, smem, pc, w, encP);
}

__global__ __launch_bounds__(256) void k3_reassemble(
    const float* __restrict__ x, const float* __restrict__ encP,
    float* __restrict__ out) {
  __shared__ __align__(16) float smem[9744];
  stageC_body(blockIdx.x, threadIdx.x, smem, x, encP, out);
}

// ===========================================================================
extern "C" void kernel_launch(void* const* d_in, const int* in_sizes, int n_in,
                              void* d_out, int out_size, void* d_ws, size_t ws_size,
                              hipStream_t stream) {
  const float* x      = (const float*)d_in[0];
  const float* w_comp = (const float*)d_in[1];
  const float* w_enc  = (const float*)d_in[2];
  float* out = (float*)d_out;

  float* pc   = (float*)d_ws;                        // 4*2*64*1600*4  = 3,276,800 B
  float* encP = (float*)((char*)d_ws + 3276800);     // 4*2*100*1600*4 = 5,120,000 B

  // Host-only capability probe (no stream interaction — capture-safe,
  // deterministic on every call; no static guards).
  int coop = 0, ncu = 0, maxb = 0;
  hipDeviceGetAttribute(&coop, hipDeviceAttributeCooperativeLaunch, 0);
  hipDeviceGetAttribute(&ncu, hipDeviceAttributeMultiprocessorCount, 0);
  hipOccupancyMaxActiveBlocksPerMultiprocessor(&maxb, k_fused, 256, 0);

  if (coop && (long)ncu * maxb >= 256) {
    void* args[] = {(void*)&x, (void*)&w_comp, (void*)&w_enc,
                    (void*)&pc, (void*)&encP, (void*)&out};
    hipLaunchCooperativeKernel(reinterpret_cast<void*>(k_fused),
                               dim3(256), dim3(256), args, 0, stream);
  } else {
    k1_conv1x1<<<dim3(200), 256, 0, stream>>>(x, w_comp, pc);
    k2_conv3x3<<<dim3(400), 256, 0, stream>>>(pc, w_enc, encP);
    k3_reassemble<<<dim3(640), 256, 0, stream>>>(x, encP, out);
  }
}

// Round 8
// 110.615 us; speedup vs baseline: 2.5207x; 2.5207x over previous
//
#include <hip/hip_runtime.h>

#define B   2
#define C   256
#define CM  64     // compressed channels
#define CE  100    // encoder out channels
#define H   40
#define W   40
#define HW  1600
#define KK  25     // K*K

// ===========================================================================
// Round-5 verified 3-kernel pipeline (best measured: 110.3-110.6 us).
// Flat 1-D grids; stage bodies byte-identical to R5.
// Lesson from R6/R7: cooperative fusion loses L2 locality across XCDs
// (FETCH 5 MB -> 32 MB, 207 us) — separate dispatches are the right structure.
// ===========================================================================

// ---------------------------------------------------------------------------
// K1: 1x1 conv 256 -> 64 as LDS GEMM, ic split 4-way over blocks.
// grid 200 = (25 px-tiles) x (4 ic-quarters) x (2 b), block 256.
// Thread tile 4 oc x 4 px. Output: fp32 partials pc[ich][b][64][1600].
// ---------------------------------------------------------------------------
__global__ __launch_bounds__(256) void k1_conv1x1(
    const float* __restrict__ x, const float* __restrict__ w,
    float* __restrict__ pc) {
  const int u = blockIdx.x;
  const int t = u % 25, ich = (u / 25) % 4, b = u / 100;
  __shared__ __align__(16) float xs[64 * 64];    // 16 KB [icl][px]
  __shared__ __align__(16) float wsA[64 * 64];   // 16 KB [icl][oc]
  const int tid = threadIdx.x;

  const float4* x4 = (const float4*)(x + ((size_t)b * C + ich * 64) * HW + t * 64);
#pragma unroll
  for (int i = 0; i < 4; i++) {
    int idx = tid + i * 256;
    ((float4*)xs)[idx] = x4[(idx >> 4) * 400 + (idx & 15)];
  }
  const float4* w4 = (const float4*)w;
#pragma unroll
  for (int i = 0; i < 4; i++) {
    int idx = tid + i * 256;
    int icq = idx >> 6, oc = idx & 63;
    float4 f = w4[oc * 64 + ich * 16 + icq];
    wsA[(icq * 4 + 0) * 64 + oc] = f.x;
    wsA[(icq * 4 + 1) * 64 + oc] = f.y;
    wsA[(icq * 4 + 2) * 64 + oc] = f.z;
    wsA[(icq * 4 + 3) * 64 + oc] = f.w;
  }
  __syncthreads();

  const int ty = tid >> 4, tx = tid & 15;
  float acc[4][4];
#pragma unroll
  for (int i = 0; i < 4; i++)
#pragma unroll
    for (int j = 0; j < 4; j++) acc[i][j] = 0.f;

#pragma unroll 4
  for (int icl = 0; icl < 64; icl++) {
    float4 a = *(const float4*)&wsA[icl * 64 + ty * 4];
    float4 bb = *(const float4*)&xs[icl * 64 + tx * 4];
    float av[4] = {a.x, a.y, a.z, a.w};
    float bv[4] = {bb.x, bb.y, bb.z, bb.w};
#pragma unroll
    for (int i = 0; i < 4; i++)
#pragma unroll
      for (int j = 0; j < 4; j++) acc[i][j] += av[i] * bv[j];
  }

  float* o = pc + ((size_t)ich * B + b) * CM * HW + t * 64 + tx * 4;
#pragma unroll
  for (int j = 0; j < 4; j++)
    *(float4*)&o[(size_t)(ty * 4 + j) * HW] =
        make_float4(acc[j][0], acc[j][1], acc[j][2], acc[j][3]);
}

// ---------------------------------------------------------------------------
// K2: 3x3 conv 64 -> 100, pad 1.
// grid 400 = (25 tiles) x (4 ocq) x (4 icq), block 256; both batches merged.
// Waves k-split 16 ic (4 each); 25 oc via float4 LDS broadcasts (each feeds
// 50 FMAs). Cross-wave tree-reduce via aliased LDS; fp32 partials to encP.
// ---------------------------------------------------------------------------
__global__ __launch_bounds__(256) void k2_conv3x3(
    const float* __restrict__ pc, const float* __restrict__ w,
    float* __restrict__ encP) {
  const int u = blockIdx.x;
  const int tile = u % 25, ocq = (u / 25) % 4, icq = u / 100;
  const int ty5 = tile / 5, tx5 = tile % 5;
  __shared__ __align__(16) float smem[3200 + 16 * 9 * 28];  // 28.9 KB
  float* cs   = smem;          // [2 b][16 icl][10x10]
  float* wsb  = smem + 3200;   // [16 icl][9 tap][28 oc]
  float* pacc = smem;          // alias for reduction (6400 <= 7232)
  const int tid = threadIdx.x;

  for (int i = tid; i < 3200; i += 256) {
    int bb = i / 1600, r = i - bb * 1600;
    int icl = r / 100, rr = r - icl * 100;
    int yy = rr / 10, xx = rr - yy * 10;
    int gy = ty5 * 8 + yy - 1, gx = tx5 * 8 + xx - 1;
    float v = 0.f;
    if (gy >= 0 && gy < H && gx >= 0 && gx < W) {
      int o = bb * 102400 + (icq * 16 + icl) * HW + gy * W + gx;
      v = pc[o] + pc[204800 + o] + pc[409600 + o] + pc[614400 + o];
    }
    cs[i] = v;
  }
  const float* wb = w + (size_t)(ocq * 25) * 576 + (size_t)(icq * 16) * 9;
  for (int i = tid; i < 3600; i += 256) {
    int ol = i / 144, r = i - ol * 144;
    wsb[r * 28 + ol] = wb[ol * 576 + r];
  }
  __syncthreads();

  const int wv = tid >> 6, lane = tid & 63, py = lane >> 3, px = lane & 7;
  float acc[50];
#pragma unroll
  for (int j = 0; j < 50; j++) acc[j] = 0.f;

#pragma unroll 1
  for (int t = 0; t < 4; t++) {
    const int icl = wv * 4 + t;
    const float* c0 = &cs[icl * 100 + py * 10 + px];
    const float* c1 = c0 + 1600;
    const float* wrow = &wsb[icl * 9 * 28];
#pragma unroll
    for (int dy = 0; dy < 3; dy++) {
#pragma unroll
      for (int dx = 0; dx < 3; dx++) {
        float x0 = c0[dy * 10 + dx];
        float x1 = c1[dy * 10 + dx];
        const float* wp = &wrow[(dy * 3 + dx) * 28];
        float4 w0 = *(const float4*)&wp[0],  w1 = *(const float4*)&wp[4];
        float4 w2 = *(const float4*)&wp[8],  w3 = *(const float4*)&wp[12];
        float4 w4v = *(const float4*)&wp[16], w5 = *(const float4*)&wp[20];
        float w6 = wp[24];
        acc[0]  += x0 * w0.x;  acc[1]  += x0 * w0.y;  acc[2]  += x0 * w0.z;  acc[3]  += x0 * w0.w;
        acc[4]  += x0 * w1.x;  acc[5]  += x0 * w1.y;  acc[6]  += x0 * w1.z;  acc[7]  += x0 * w1.w;
        acc[8]  += x0 * w2.x;  acc[9]  += x0 * w2.y;  acc[10] += x0 * w2.z;  acc[11] += x0 * w2.w;
        acc[12] += x0 * w3.x;  acc[13] += x0 * w3.y;  acc[14] += x0 * w3.z;  acc[15] += x0 * w3.w;
        acc[16] += x0 * w4v.x; acc[17] += x0 * w4v.y; acc[18] += x0 * w4v.z; acc[19] += x0 * w4v.w;
        acc[20] += x0 * w5.x;  acc[21] += x0 * w5.y;  acc[22] += x0 * w5.z;  acc[23] += x0 * w5.w;
        acc[24] += x0 * w6;
        acc[25] += x1 * w0.x;  acc[26] += x1 * w0.y;  acc[27] += x1 * w0.z;  acc[28] += x1 * w0.w;
        acc[29] += x1 * w1.x;  acc[30] += x1 * w1.y;  acc[31] += x1 * w1.z;  acc[32] += x1 * w1.w;
        acc[33] += x1 * w2.x;  acc[34] += x1 * w2.y;  acc[35] += x1 * w2.z;  acc[36] += x1 * w2.w;
        acc[37] += x1 * w3.x;  acc[38] += x1 * w3.y;  acc[39] += x1 * w3.z;  acc[40] += x1 * w3.w;
        acc[41] += x1 * w4v.x; acc[42] += x1 * w4v.y; acc[43] += x1 * w4v.z; acc[44] += x1 * w4v.w;
        acc[45] += x1 * w5.x;  acc[46] += x1 * w5.y;  acc[47] += x1 * w5.z;  acc[48] += x1 * w5.w;
        acc[49] += x1 * w6;
      }
    }
  }

  __syncthreads();
  if (wv == 1 || wv == 3) {
    const int slot = wv >> 1;
#pragma unroll
    for (int j = 0; j < 50; j++) pacc[slot * 3200 + j * 64 + lane] = acc[j];
  }
  __syncthreads();
  if (wv == 0 || wv == 2) {
    const int slot = wv >> 1;
#pragma unroll
    for (int j = 0; j < 50; j++) acc[j] += pacc[slot * 3200 + j * 64 + lane];
  }
  __syncthreads();
  if (wv == 2) {
#pragma unroll
    for (int j = 0; j < 50; j++) pacc[j * 64 + lane] = acc[j];
  }
  __syncthreads();
  if (wv == 0) {
    const int base_px = (ty5 * 8 + py) * W + tx5 * 8 + px;
#pragma unroll
    for (int bb = 0; bb < 2; bb++)
#pragma unroll
      for (int ol = 0; ol < 25; ol++)
        encP[(((size_t)icq * 2 + bb) * CE + ocq * 25 + ol) * HW + base_px] =
            acc[bb * 25 + ol] + pacc[(bb * 25 + ol) * 64 + lane];
  }
}

// ---------------------------------------------------------------------------
// K3: softmax over 25 (summing 4 enc partials) + reassembly.
// grid 640 = (80 = i0*2+jh) x (4 cq) x (2 b), block 256.
// Phase 1 (80 threads): softmax -> wlds. Phase 2: lane = channel, 9-wide
// x register cache, float4 weight broadcasts, float4 stores.
// ---------------------------------------------------------------------------
__global__ __launch_bounds__(256) void k3_reassemble(
    const float* __restrict__ x, const float* __restrict__ encP,
    float* __restrict__ out) {
  const int u = blockIdx.x;
  const int bx = u % 80;
  const int i0 = bx >> 1;
  const int jh = bx & 1;
  const int cq = (u / 80) % 4;
  const int b = u / 320;

  __shared__ __align__(16) float wlds[20 * KK * 4];  // 8 KB  [j0l][k][d]
  __shared__ float xsm[64 * 121];                    // 31 KB [c][r*24 + t]

  const int tid = threadIdx.x;

  if (tid < 80) {
    const int e = jh * 80 + tid;
    const int j0 = e >> 2, d = e & 3;
    const int off = ((e >= 80) ? 2 : 0) + (e & 1);
    const int col = ((e >= 80) ? (j0 - 20) : j0) * 2 + (d >> 1);
    const float* ep = encP + (size_t)b * CE * HW + i0 * W + col;
    float v[KK];
    float m = -1e30f;
#pragma unroll
    for (int k = 0; k < KK; k++) {
      int o = (k * 4 + off) * HW;
      v[k] = ep[o] + ep[320000 + o] + ep[640000 + o] + ep[960000 + o];
      m = fmaxf(m, v[k]);
    }
    float s = 0.f;
#pragma unroll
    for (int k = 0; k < KK; k++) {
      v[k] = expf(v[k] - m);
      s += v[k];
    }
    const float inv = 1.f / s;
    const int j0l = j0 - jh * 20;
#pragma unroll
    for (int k = 0; k < KK; k++) wlds[(j0l * KK + k) * 4 + d] = v[k] * inv;
  }

  const float* xb = x + ((size_t)b * C + cq * 64) * HW;
  for (int i = tid; i < 64 * 120; i += 256) {
    int c = i / 120;
    int rr = i % 120;
    int r = rr / 24, t = rr % 24;
    int gy = i0 - 2 + r;
    int gx = jh * 20 + t - 2;
    float v = 0.f;
    if (gy >= 0 && gy < H && gx >= 0 && gx < W) v = xb[c * HW + gy * W + gx];
    xsm[c * 121 + r * 24 + t] = v;
  }
  __syncthreads();

  const int wv = tid >> 6;
  const int lane = tid & 63;
  const int j0b = wv * 5;
  const float* xrow = &xsm[lane * 121];
  float* ob = out + (((size_t)b * C + cq * 64 + lane) * 6400) + i0 * 160;

  float a[5][4];
#pragma unroll
  for (int jj = 0; jj < 5; jj++)
#pragma unroll
    for (int d = 0; d < 4; d++) a[jj][d] = 0.f;

#pragma unroll
  for (int ki = 0; ki < 5; ki++) {
    float xv[9];
    const float* xr = &xrow[ki * 24 + j0b];
#pragma unroll
    for (int q = 0; q < 9; q++) xv[q] = xr[q];
    const float* wrow = &wlds[(j0b * KK + ki * 5) * 4];
#pragma unroll
    for (int jj = 0; jj < 5; jj++) {
#pragma unroll
      for (int kj = 0; kj < 5; kj++) {
        float4 w4 = *(const float4*)&wrow[(jj * KK + kj) * 4];
        float xvv = xv[jj + kj];
        a[jj][0] += xvv * w4.x;
        a[jj][1] += xvv * w4.y;
        a[jj][2] += xvv * w4.z;
        a[jj][3] += xvv * w4.w;
      }
    }
  }
#pragma unroll
  for (int jj = 0; jj < 5; jj++)
    *(float4*)&ob[(jh * 20 + j0b + jj) * 4] =
        make_float4(a[jj][0], a[jj][1], a[jj][2], a[jj][3]);
}

// ---------------------------------------------------------------------------
extern "C" void kernel_launch(void* const* d_in, const int* in_sizes, int n_in,
                              void* d_out, int out_size, void* d_ws, size_t ws_size,
                              hipStream_t stream) {
  const float* x      = (const float*)d_in[0];
  const float* w_comp = (const float*)d_in[1];
  const float* w_enc  = (const float*)d_in[2];
  float* out = (float*)d_out;

  float* pc   = (float*)d_ws;                        // 4*2*64*1600*4  = 3,276,800 B
  float* encP = (float*)((char*)d_ws + 3276800);     // 4*2*100*1600*4 = 5,120,000 B

  k1_conv1x1<<<dim3(200), 256, 0, stream>>>(x, w_comp, pc);
  k2_conv3x3<<<dim3(400), 256, 0, stream>>>(pc, w_enc, encP);
  k3_reassemble<<<dim3(640), 256, 0, stream>>>(x, encP, out);
}